// Round 2
// baseline (670.797 us; speedup 1.0000x reference)
//
#include <hip/hip_runtime.h>
#include <hip/hip_bf16.h>

typedef __attribute__((ext_vector_type(8))) short short8;
typedef __attribute__((ext_vector_type(8))) unsigned short ushort8;
typedef __attribute__((ext_vector_type(4))) float floatx4;
typedef __attribute__((ext_vector_type(4))) unsigned int uint4v;
typedef __attribute__((ext_vector_type(2))) unsigned int uint2v;

#define DEVINL static __device__ __forceinline__

DEVINL float b2f(unsigned short s){ union{unsigned u; float f;} v; v.u=((unsigned)s)<<16; return v.f; }
DEVINL unsigned fbits(float f){ union{float f; unsigned u;} v; v.f=f; return v.u; }
// pack two floats to bf16 pair (f0 -> low16, f1 -> high16), round-half-up via +0x8000
DEVINL unsigned pack2(float f0, float f1){
  return __builtin_amdgcn_perm(fbits(f1)+0x8000u, fbits(f0)+0x8000u, 0x07060302u);
}
DEVINL float tanh_fast(float v){
  float ax = fabsf(v);
  float ex = __expf(-2.f*ax);
  float th = (1.f - ex)*__builtin_amdgcn_rcpf(1.f + ex);
  return copysignf(th, v);
}
DEVINL void gload_lds16(const void* g, void* l){
  __builtin_amdgcn_global_load_lds(
    (const __attribute__((address_space(1))) unsigned int*)g,
    (__attribute__((address_space(3))) unsigned int*)l, 16, 0, 0);
}

constexpr int Sc=256, Hc=768, Nc=128, HIDc=1024, Lc=16;

// ---------------- gather + bf16 cast: con[b*N+n][768] ----------------
__global__ __launch_bounds__(256) void k_gather(const float* __restrict__ AH,
                                                const int* __restrict__ ST,
                                                unsigned short* __restrict__ con){
  int row = blockIdx.x;            // b*128 + n
  int b = row >> 7;
  int st = ST[row];
  const float* src = AH + ((size_t)(b*Sc + st))*Hc;
  unsigned short* dst = con + (size_t)row*Hc;
  int t = threadIdx.x;
  if (t < 192) {
    float4 v = reinterpret_cast<const float4*>(src)[t];
    uint2v o = { pack2(v.x, v.y), pack2(v.z, v.w) };
    *reinterpret_cast<uint2v*>(dst + 4*t) = o;
  }
}

// ---------- W1m (rows 2304..3071 of W1) -> bf16 fragments, coalesced ----------
// layout: [htg(64)][kc(24)][lane(64)][e(8)], lane = col | (seg<<4), k = kc*32+seg*8+e
__global__ __launch_bounds__(256) void k_w1m(const float* __restrict__ W1,
                                             unsigned short* __restrict__ w1mF){
  int sid = blockIdx.x*256 + threadIdx.x;     // 0..98303
  int lane = sid & 63, kcq = (sid >> 6) % 24, htg = sid / (24*64);
  int col = lane & 15, seg = lane >> 4;
  int h = (htg >> 3)*128 + (htg & 7)*16 + col;
  const float* wp = W1 + (size_t)(2304 + kcq*32 + seg*8)*1024 + h;
  uint4v d;
  d[0] = pack2(wp[0],      wp[1024]);
  d[1] = pack2(wp[2*1024], wp[3*1024]);
  d[2] = pack2(wp[4*1024], wp[5*1024]);
  d[3] = pack2(wp[6*1024], wp[7*1024]);
  *reinterpret_cast<uint4v*>(w1mF + (size_t)sid*8) = d;
}

// ---------- combined P/Q weights -> bf16 fragments ----------
// wPQF: [ht(128)][kc(24)][lane(64)][e(8)]; h'<1024: W1[k][h]+W1[1536+k][h]; else W1[768+k][h]-W1[1536+k][h]
__global__ __launch_bounds__(256) void k_wpq(const float* __restrict__ W1,
                                             unsigned short* __restrict__ wPQF){
  int sid = blockIdx.x*256 + threadIdx.x;     // 0..196607
  int lane = sid & 63, kcq = (sid >> 6) % 24, ht = sid / (24*64);
  int col = lane & 15, seg = lane >> 4;
  int hp = ht*16 + col;
  int kb = kcq*32 + seg*8;
  uint4v d;
  if (hp < 1024) {
    const float* w0 = W1 + (size_t)kb*1024 + hp;
    const float* wd = W1 + (size_t)(1536+kb)*1024 + hp;
    d[0] = pack2(w0[0]+wd[0],           w0[1024]+wd[1024]);
    d[1] = pack2(w0[2*1024]+wd[2*1024], w0[3*1024]+wd[3*1024]);
    d[2] = pack2(w0[4*1024]+wd[4*1024], w0[5*1024]+wd[5*1024]);
    d[3] = pack2(w0[6*1024]+wd[6*1024], w0[7*1024]+wd[7*1024]);
  } else {
    int hq = hp - 1024;
    const float* wc = W1 + (size_t)(768+kb)*1024 + hq;
    const float* wd = W1 + (size_t)(1536+kb)*1024 + hq;
    d[0] = pack2(wc[0]-wd[0],           wc[1024]-wd[1024]);
    d[1] = pack2(wc[2*1024]-wd[2*1024], wc[3*1024]-wd[3*1024]);
    d[2] = pack2(wc[4*1024]-wd[4*1024], wc[5*1024]-wd[5*1024]);
    d[3] = pack2(wc[6*1024]-wd[6*1024], wc[7*1024]-wd[7*1024]);
  }
  *reinterpret_cast<uint4v*>(wPQF + (size_t)sid*8) = d;
}

// ---------------- P/Q via MFMA: out[512 rows][2048 cols] ----------------
__global__ __launch_bounds__(256) void k_pq(const unsigned short* __restrict__ con,
                                            const unsigned short* __restrict__ wPQF,
                                            float* __restrict__ P, float* __restrict__ Q){
  int rg = blockIdx.x >> 4, hg = blockIdx.x & 15;     // 16 rowgroups x 16 colgroups
  int t = threadIdx.x, w = t >> 6, lane = t & 63;
  int colh = lane & 15, rseg = lane >> 4;
  floatx4 zero = {0.f,0.f,0.f,0.f};
  floatx4 acc[2][2] = {{zero,zero},{zero,zero}};
  const unsigned short* a0p = con + (size_t)(rg*32 + colh)*Hc + rseg*8;
  const unsigned short* a1p = a0p + 16*Hc;
  const unsigned short* b0p = wPQF + (((size_t)((hg*8 + w*2)*24)) << 9) + (lane << 3);
  const unsigned short* b1p = b0p + (24 << 9);
  #pragma unroll
  for (int kc = 0; kc < 24; ++kc) {
    short8 af0 = *reinterpret_cast<const short8*>(a0p + kc*32);
    short8 af1 = *reinterpret_cast<const short8*>(a1p + kc*32);
    short8 bf0 = *reinterpret_cast<const short8*>(b0p + ((size_t)kc << 9));
    short8 bf1 = *reinterpret_cast<const short8*>(b1p + ((size_t)kc << 9));
    acc[0][0] = __builtin_amdgcn_mfma_f32_16x16x32_bf16(af0, bf0, acc[0][0], 0,0,0);
    acc[0][1] = __builtin_amdgcn_mfma_f32_16x16x32_bf16(af0, bf1, acc[0][1], 0,0,0);
    acc[1][0] = __builtin_amdgcn_mfma_f32_16x16x32_bf16(af1, bf0, acc[1][0], 0,0,0);
    acc[1][1] = __builtin_amdgcn_mfma_f32_16x16x32_bf16(af1, bf1, acc[1][1], 0,0,0);
  }
  #pragma unroll
  for (int m = 0; m < 2; ++m)
    #pragma unroll
    for (int n = 0; n < 2; ++n)
      #pragma unroll
      for (int rr = 0; rr < 4; ++rr) {
        int row = rg*32 + m*16 + rseg*4 + rr;
        int hp = hg*128 + w*32 + n*16 + colh;
        float val = acc[m][n][rr];
        if (hg < 8) P[(size_t)row*HIDc + hp] = val;
        else        Q[(size_t)row*HIDc + (hp - 1024)] = val;
      }
}

// ---------------- fused main kernel: one block per (b,i) ----------------
__global__ __launch_bounds__(256, 2) void k_main(const unsigned short* __restrict__ con,
    const unsigned short* __restrict__ w1mF,
    const float* __restrict__ P, const float* __restrict__ Q, const float* __restrict__ b1,
    const float* __restrict__ W2, const float* __restrict__ b2, float* __restrict__ out){
  __shared__ float a_row[768];
  __shared__ unsigned short A_lds[2][8][64][8];
  __shared__ unsigned short B_lds[2][8][64][8];
  __shared__ unsigned short hidF[8][4][64][8];   // [jt][ks][lane][e], XOR-swizzled
  __shared__ unsigned short W2_lds[4][64][8];

  int bi = blockIdx.x;                 // b*128 + i
  int b = bi >> 7, i = bi & 127;
  int t = threadIdx.x, w = t >> 6, lane = t & 63;
  int wr = w >> 1, wcq = w & 1;        // 2x2 wave grid
  int bN = b * Nc;
  int colh = lane & 15, rbase = (lane >> 4) << 2;

  // per-thread staging invariants
  int jt0 = t >> 6, ln0 = t & 63;
  int jt1 = jt0 + 4;
  int jA = (jt0 << 4) | (t & 15);
  int gkoff = ((t >> 4) & 3) << 3;
  const unsigned short* conA_base = con + (size_t)(bN + jA)*Hc + gkoff;
  const unsigned short* conB_base = conA_base + (size_t)64*Hc;
  char* hidb = reinterpret_cast<char*>(&hidF[0][0][0][0]);

  for (int k = t; k < 768; k += 256) a_row[k] = b2f(con[(size_t)(bN + i)*Hc + k]);
  __syncthreads();

  floatx4 zero = {0.f,0.f,0.f,0.f};
  floatx4 acc2[2] = {zero, zero};
  ushort8 c0a, c0b, c1a, c1b;

  // -------- prologue: stage A(0), B(0), con(1) --------
  {
    ushort8 ca = *reinterpret_cast<const ushort8*>(conA_base);
    ushort8 cb = *reinterpret_cast<const ushort8*>(conB_base);
    floatx4 av0 = *reinterpret_cast<const floatx4*>(&a_row[gkoff]);
    floatx4 av1 = *reinterpret_cast<const floatx4*>(&a_row[gkoff + 4]);
    uint4v dA, dB;
    dA[0]=pack2(av0[0]*b2f(ca[0]), av0[1]*b2f(ca[1])); dA[1]=pack2(av0[2]*b2f(ca[2]), av0[3]*b2f(ca[3]));
    dA[2]=pack2(av1[0]*b2f(ca[4]), av1[1]*b2f(ca[5])); dA[3]=pack2(av1[2]*b2f(ca[6]), av1[3]*b2f(ca[7]));
    dB[0]=pack2(av0[0]*b2f(cb[0]), av0[1]*b2f(cb[1])); dB[1]=pack2(av0[2]*b2f(cb[2]), av0[3]*b2f(cb[3]));
    dB[2]=pack2(av1[0]*b2f(cb[4]), av1[1]*b2f(cb[5])); dB[3]=pack2(av1[2]*b2f(cb[6]), av1[3]*b2f(cb[7]));
    *reinterpret_cast<uint4v*>(&A_lds[0][jt0][ln0][0]) = dA;
    *reinterpret_cast<uint4v*>(&A_lds[0][jt1][ln0][0]) = dB;
    gload_lds16(w1mF + (((size_t)((0*8 + 2*w)*24 + 0)) << 9) + (lane << 3), &B_lds[0][2*w][0][0]);
    gload_lds16(w1mF + (((size_t)((0*8 + 2*w + 1)*24 + 0)) << 9) + (lane << 3), &B_lds[0][2*w+1][0][0]);
    c0a = *reinterpret_cast<const ushort8*>(conA_base + 32);
    c0b = *reinterpret_cast<const ushort8*>(conB_base + 32);
  }
  __syncthreads();

#define KSTEP(KC, CURA, CURB, NXTA, NXTB)                                             \
{                                                                                      \
  const int kc = (KC);                                                                 \
  const int cur = kc & 1, nxt = cur ^ 1;                                               \
  const int kc1 = (kc + 1) % 24;                                                       \
  const int kc2 = (kc + 2) % 24;                                                       \
  const int hc1 = (kc == 23) ? ((hc + 1) & 7) : hc;                                    \
  gload_lds16(w1mF + (((size_t)((hc1*8 + 2*w)*24 + kc1)) << 9) + (lane << 3),          \
              &B_lds[nxt][2*w][0][0]);                                                 \
  gload_lds16(w1mF + (((size_t)((hc1*8 + 2*w + 1)*24 + kc1)) << 9) + (lane << 3),      \
              &B_lds[nxt][2*w+1][0][0]);                                               \
  NXTA = *reinterpret_cast<const ushort8*>(conA_base + kc2*32);                        \
  NXTB = *reinterpret_cast<const ushort8*>(conB_base + kc2*32);                        \
  {                                                                                    \
    short8 af[4], bfr[4];                                                              \
    _Pragma("unroll")                                                                  \
    for (int m = 0; m < 4; ++m) af[m] = *reinterpret_cast<const short8*>(&A_lds[cur][wr*4+m][lane][0]); \
    _Pragma("unroll")                                                                  \
    for (int n = 0; n < 4; ++n) bfr[n] = *reinterpret_cast<const short8*>(&B_lds[cur][wcq*4+n][lane][0]); \
    _Pragma("unroll")                                                                  \
    for (int m = 0; m < 4; ++m)                                                        \
      _Pragma("unroll")                                                                \
      for (int n = 0; n < 4; ++n)                                                      \
        acc[m][n] = __builtin_amdgcn_mfma_f32_16x16x32_bf16(af[m], bfr[n], acc[m][n], 0,0,0); \
  }                                                                                    \
  {                                                                                    \
    floatx4 av0 = *reinterpret_cast<const floatx4*>(&a_row[kc1*32 + gkoff]);           \
    floatx4 av1 = *reinterpret_cast<const floatx4*>(&a_row[kc1*32 + gkoff + 4]);       \
    uint4v dA, dB;                                                                     \
    dA[0]=pack2(av0[0]*b2f(CURA[0]), av0[1]*b2f(CURA[1]));                             \
    dA[1]=pack2(av0[2]*b2f(CURA[2]), av0[3]*b2f(CURA[3]));                             \
    dA[2]=pack2(av1[0]*b2f(CURA[4]), av1[1]*b2f(CURA[5]));                             \
    dA[3]=pack2(av1[2]*b2f(CURA[6]), av1[3]*b2f(CURA[7]));                             \
    dB[0]=pack2(av0[0]*b2f(CURB[0]), av0[1]*b2f(CURB[1]));                             \
    dB[1]=pack2(av0[2]*b2f(CURB[2]), av0[3]*b2f(CURB[3]));                             \
    dB[2]=pack2(av1[0]*b2f(CURB[4]), av1[1]*b2f(CURB[5]));                             \
    dB[3]=pack2(av1[2]*b2f(CURB[6]), av1[3]*b2f(CURB[7]));                             \
    *reinterpret_cast<uint4v*>(&A_lds[nxt][jt0][ln0][0]) = dA;                         \
    *reinterpret_cast<uint4v*>(&A_lds[nxt][jt1][ln0][0]) = dB;                         \
  }                                                                                    \
  __syncthreads();                                                                     \
}

  for (int hc = 0; hc < 8; ++hc) {
    floatx4 acc[4][4];
    #pragma unroll
    for (int m = 0; m < 4; ++m)
      #pragma unroll
      for (int n = 0; n < 4; ++n) acc[m][n] = zero;

    #pragma unroll
    for (int kcp = 0; kcp < 12; ++kcp) {
      KSTEP(2*kcp,     c0a, c0b, c1a, c1b);
      KSTEP(2*kcp + 1, c1a, c1b, c0a, c0b);
    }

    // -------- epilogue: W2 stage + tanh + hidF + GEMM2 --------
    {
      int ksW = t >> 6, lnW = t & 63, colW = lnW & 15, sW = lnW >> 4;
      const float* w2p = W2 + (size_t)(hc*128 + ksW*4 + sW)*Lc + colW;
      uint4v dW;
      dW[0] = pack2(w2p[0],     w2p[256]);
      dW[1] = pack2(w2p[2*256], w2p[3*256]);
      dW[2] = pack2(w2p[4*256], w2p[5*256]);
      dW[3] = pack2(w2p[6*256], w2p[7*256]);
      *reinterpret_cast<uint4v*>(&W2_lds[ksW][lnW][0]) = dW;
    }
    float pb[4];
    #pragma unroll
    for (int n = 0; n < 4; ++n) {
      int gh = hc*128 + wcq*64 + n*16 + colh;
      pb[n] = P[(size_t)(bN + i)*HIDc + gh] + b1[gh];
    }
    int ks_h = colh >> 2;
    unsigned swz = (unsigned)(colh & 7) << 4;
    #pragma unroll
    for (int m = 0; m < 4; ++m) {
      int jt = wr*4 + m;
      #pragma unroll
      for (int r = 0; r < 4; ++r) {
        int jl = wr*64 + m*16 + rbase + r;
        const float* qp = Q + (size_t)(bN + jl)*HIDc + hc*128 + wcq*64 + colh;
        float v0 = acc[m][0][r] + pb[0] + qp[0];
        float v1 = acc[m][1][r] + pb[1] + qp[16];
        float v2 = acc[m][2][r] + pb[2] + qp[32];
        float v3 = acc[m][3][r] + pb[3] + qp[48];
        unsigned lo = pack2(tanh_fast(v0), tanh_fast(v1));
        unsigned hi = pack2(tanh_fast(v2), tanh_fast(v3));
        int lnH = (rbase + r) | ((colh & 3) << 4);
        unsigned off = ((unsigned)(((jt*4 + ks_h)*64 + lnH)*16 + 8*wcq)) ^ swz;
        uint2v dv = { lo, hi };
        *reinterpret_cast<uint2v*>(hidb + off) = dv;
      }
    }
    __syncthreads();
    #pragma unroll
    for (int jt2 = 0; jt2 < 2; ++jt2) {
      int jt = w*2 + jt2;
      #pragma unroll
      for (int ks = 0; ks < 4; ++ks) {
        unsigned key = (unsigned)((ks*4 + (lane >> 4)) & 7) << 4;
        unsigned roff = ((unsigned)(((jt*4 + ks)*64 + lane)*16)) ^ key;
        short8 a2  = *reinterpret_cast<const short8*>(hidb + roff);
        short8 b2v = *reinterpret_cast<const short8*>(&W2_lds[ks][lane][0]);
        acc2[jt2] = __builtin_amdgcn_mfma_f32_16x16x32_bf16(a2, b2v, acc2[jt2], 0,0,0);
      }
    }
    __syncthreads();
  }
#undef KSTEP

  float bl = b2[colh];
  #pragma unroll
  for (int jt2 = 0; jt2 < 2; ++jt2) {
    int jt = w*2 + jt2;
    #pragma unroll
    for (int r = 0; r < 4; ++r) {
      int jl = jt*16 + rbase + r;
      out[((size_t)bi*Nc + jl)*Lc + colh] = acc2[jt2][r] + bl;
    }
  }
}

extern "C" void kernel_launch(void* const* d_in, const int* in_sizes, int n_in,
                              void* d_out, int out_size, void* d_ws, size_t ws_size,
                              hipStream_t stream) {
  const float* AH = (const float*)d_in[0];
  const int*   ST = (const int*)d_in[1];
  const float* W1 = (const float*)d_in[2];
  const float* b1 = (const float*)d_in[3];
  const float* W2 = (const float*)d_in[4];
  const float* b2 = (const float*)d_in[5];
  float* out = (float*)d_out;

  char* ws = (char*)d_ws;
  unsigned short* con  = (unsigned short*)ws;                //   786,432 B
  unsigned short* w1mF = (unsigned short*)(ws +   786432);   // 1,572,864 B
  unsigned short* wPQF = (unsigned short*)(ws +  2359296);   // 3,145,728 B
  float* P = (float*)(ws + 5505024);                         // 2,097,152 B
  float* Q = (float*)(ws + 7602176);                         // 2,097,152 B

  k_gather<<<512, 256, 0, stream>>>(AH, ST, con);
  k_w1m<<<384, 256, 0, stream>>>(W1, w1mF);
  k_wpq<<<768, 256, 0, stream>>>(W1, wPQF);
  k_pq<<<256, 256, 0, stream>>>(con, wPQF, P, Q);
  k_main<<<512, 256, 0, stream>>>(con, w1mF, P, Q, b1, W2, b2, out);
}

// Round 3
// 549.619 us; speedup vs baseline: 1.2205x; 1.2205x over previous
//
#include <hip/hip_runtime.h>
#include <hip/hip_bf16.h>

typedef __attribute__((ext_vector_type(8))) short short8;
typedef __attribute__((ext_vector_type(8))) unsigned short ushort8;
typedef __attribute__((ext_vector_type(4))) float floatx4;
typedef __attribute__((ext_vector_type(4))) unsigned int uint4v;
typedef __attribute__((ext_vector_type(2))) unsigned int uint2v;

#define DEVINL static __device__ __forceinline__

DEVINL float b2f(unsigned short s){ union{unsigned u; float f;} v; v.u=((unsigned)s)<<16; return v.f; }
DEVINL unsigned fbits(float f){ union{float f; unsigned u;} v; v.f=f; return v.u; }
// pack two floats to bf16 pair (f0 -> low16, f1 -> high16), round-half-up via +0x8000
DEVINL unsigned pack2(float f0, float f1){
  return __builtin_amdgcn_perm(fbits(f1)+0x8000u, fbits(f0)+0x8000u, 0x07060302u);
}
DEVINL float tanh_fast(float v){
  float ax = fabsf(v);
  float ex = __expf(-2.f*ax);
  float th = (1.f - ex)*__builtin_amdgcn_rcpf(1.f + ex);
  return copysignf(th, v);
}

constexpr int Sc=256, Hc=768, Nc=128, HIDc=1024, Lc=16;

// ---------------- gather + bf16 cast: con[b*N+n][768] ----------------
__global__ __launch_bounds__(256) void k_gather(const float* __restrict__ AH,
                                                const int* __restrict__ ST,
                                                unsigned short* __restrict__ con){
  int row = blockIdx.x;            // b*128 + n
  int b = row >> 7;
  int st = ST[row];
  const float* src = AH + ((size_t)(b*Sc + st))*Hc;
  unsigned short* dst = con + (size_t)row*Hc;
  int t = threadIdx.x;
  if (t < 192) {
    float4 v = reinterpret_cast<const float4*>(src)[t];
    uint2v o = { pack2(v.x, v.y), pack2(v.z, v.w) };
    *reinterpret_cast<uint2v*>(dst + 4*t) = o;
  }
}

// ---------- W1m (rows 2304..3071 of W1) -> bf16 fragments, coalesced ----------
// layout: [htg(64)][kc(24)][lane(64)][e(8)], lane = col | (seg<<4), k = kc*32+seg*8+e
__global__ __launch_bounds__(256) void k_w1m(const float* __restrict__ W1,
                                             unsigned short* __restrict__ w1mF){
  int sid = blockIdx.x*256 + threadIdx.x;     // 0..98303
  int lane = sid & 63, kcq = (sid >> 6) % 24, htg = sid / (24*64);
  int col = lane & 15, seg = lane >> 4;
  int h = (htg >> 3)*128 + (htg & 7)*16 + col;
  const float* wp = W1 + (size_t)(2304 + kcq*32 + seg*8)*1024 + h;
  uint4v d;
  d[0] = pack2(wp[0],      wp[1024]);
  d[1] = pack2(wp[2*1024], wp[3*1024]);
  d[2] = pack2(wp[4*1024], wp[5*1024]);
  d[3] = pack2(wp[6*1024], wp[7*1024]);
  *reinterpret_cast<uint4v*>(w1mF + (size_t)sid*8) = d;
}

// ---------- combined P/Q weights -> bf16 fragments ----------
// wPQF: [ht(128)][kc(24)][lane(64)][e(8)]; h'<1024: W1[k][h]+W1[1536+k][h]; else W1[768+k][h]-W1[1536+k][h]
__global__ __launch_bounds__(256) void k_wpq(const float* __restrict__ W1,
                                             unsigned short* __restrict__ wPQF){
  int sid = blockIdx.x*256 + threadIdx.x;     // 0..196607
  int lane = sid & 63, kcq = (sid >> 6) % 24, ht = sid / (24*64);
  int col = lane & 15, seg = lane >> 4;
  int hp = ht*16 + col;
  int kb = kcq*32 + seg*8;
  uint4v d;
  if (hp < 1024) {
    const float* w0 = W1 + (size_t)kb*1024 + hp;
    const float* wd = W1 + (size_t)(1536+kb)*1024 + hp;
    d[0] = pack2(w0[0]+wd[0],           w0[1024]+wd[1024]);
    d[1] = pack2(w0[2*1024]+wd[2*1024], w0[3*1024]+wd[3*1024]);
    d[2] = pack2(w0[4*1024]+wd[4*1024], w0[5*1024]+wd[5*1024]);
    d[3] = pack2(w0[6*1024]+wd[6*1024], w0[7*1024]+wd[7*1024]);
  } else {
    int hq = hp - 1024;
    const float* wc = W1 + (size_t)(768+kb)*1024 + hq;
    const float* wd = W1 + (size_t)(1536+kb)*1024 + hq;
    d[0] = pack2(wc[0]-wd[0],           wc[1024]-wd[1024]);
    d[1] = pack2(wc[2*1024]-wd[2*1024], wc[3*1024]-wd[3*1024]);
    d[2] = pack2(wc[4*1024]-wd[4*1024], wc[5*1024]-wd[5*1024]);
    d[3] = pack2(wc[6*1024]-wd[6*1024], wc[7*1024]-wd[7*1024]);
  }
  *reinterpret_cast<uint4v*>(wPQF + (size_t)sid*8) = d;
}

// ---------------- P/Q via MFMA: out[512 rows][2048 cols] ----------------
__global__ __launch_bounds__(256) void k_pq(const unsigned short* __restrict__ con,
                                            const unsigned short* __restrict__ wPQF,
                                            float* __restrict__ P, float* __restrict__ Q){
  int rg = blockIdx.x >> 4, hg = blockIdx.x & 15;     // 16 rowgroups x 16 colgroups
  int t = threadIdx.x, w = t >> 6, lane = t & 63;
  int colh = lane & 15, rseg = lane >> 4;
  floatx4 zero = {0.f,0.f,0.f,0.f};
  floatx4 acc[2][2] = {{zero,zero},{zero,zero}};
  const unsigned short* a0p = con + (size_t)(rg*32 + colh)*Hc + rseg*8;
  const unsigned short* a1p = a0p + 16*Hc;
  const unsigned short* b0p = wPQF + (((size_t)((hg*8 + w*2)*24)) << 9) + (lane << 3);
  const unsigned short* b1p = b0p + (24 << 9);
  #pragma unroll
  for (int kc = 0; kc < 24; ++kc) {
    short8 af0 = *reinterpret_cast<const short8*>(a0p + kc*32);
    short8 af1 = *reinterpret_cast<const short8*>(a1p + kc*32);
    short8 bf0 = *reinterpret_cast<const short8*>(b0p + ((size_t)kc << 9));
    short8 bf1 = *reinterpret_cast<const short8*>(b1p + ((size_t)kc << 9));
    acc[0][0] = __builtin_amdgcn_mfma_f32_16x16x32_bf16(af0, bf0, acc[0][0], 0,0,0);
    acc[0][1] = __builtin_amdgcn_mfma_f32_16x16x32_bf16(af0, bf1, acc[0][1], 0,0,0);
    acc[1][0] = __builtin_amdgcn_mfma_f32_16x16x32_bf16(af1, bf0, acc[1][0], 0,0,0);
    acc[1][1] = __builtin_amdgcn_mfma_f32_16x16x32_bf16(af1, bf1, acc[1][1], 0,0,0);
  }
  #pragma unroll
  for (int m = 0; m < 2; ++m)
    #pragma unroll
    for (int n = 0; n < 2; ++n)
      #pragma unroll
      for (int rr = 0; rr < 4; ++rr) {
        int row = rg*32 + m*16 + rseg*4 + rr;
        int hp = hg*128 + w*32 + n*16 + colh;
        float val = acc[m][n][rr];
        if (hg < 8) P[(size_t)row*HIDc + hp] = val;
        else        Q[(size_t)row*HIDc + (hp - 1024)] = val;
      }
}

// ---------------- fused main kernel: one block per (b,i) ----------------
__global__ __launch_bounds__(256, 2) void k_main(const unsigned short* __restrict__ con,
    const unsigned short* __restrict__ w1mF,
    const float* __restrict__ P, const float* __restrict__ Q, const float* __restrict__ b1,
    const float* __restrict__ W2, const float* __restrict__ b2, float* __restrict__ out){
  __shared__ float a_row[768];
  __shared__ unsigned short A_lds[2][8][64][8];
  __shared__ unsigned short B_lds[2][8][64][8];
  __shared__ unsigned short hidF[8][4][64][8];   // [jt][ks][lane][e], XOR-swizzled
  __shared__ unsigned short W2_lds[4][64][8];

  int bi = blockIdx.x;                 // b*128 + i
  int b = bi >> 7, i = bi & 127;
  int t = threadIdx.x, w = t >> 6, lane = t & 63;
  int wr = w >> 1, wcq = w & 1;        // 2x2 wave grid
  int bN = b * Nc;
  int colh = lane & 15, rbase = (lane >> 4) << 2;

  // per-thread staging invariants (thread stages slots jt0 and jt1 at ln0)
  int jt0 = t >> 6, ln0 = t & 63;
  int jt1 = jt0 + 4;
  int jA = (jt0 << 4) | (t & 15);
  int gkoff = ((t >> 4) & 3) << 3;
  const unsigned short* conA_base = con + (size_t)(bN + jA)*Hc + gkoff;
  const unsigned short* conB_base = conA_base + (size_t)64*Hc;
  // B fragment global base for (jt, kc): w1mF + ((hc*8+jt)*24+kc)*512 + ln0*8
  const unsigned short* w1A_base = w1mF + ((size_t)jt0*24 << 9) + (ln0 << 3);
  const unsigned short* w1B_base = w1mF + ((size_t)jt1*24 << 9) + (ln0 << 3);
  char* hidb = reinterpret_cast<char*>(&hidF[0][0][0][0]);

  for (int k = t; k < 768; k += 256) a_row[k] = b2f(con[(size_t)(bN + i)*Hc + k]);
  __syncthreads();

  floatx4 zero = {0.f,0.f,0.f,0.f};
  floatx4 acc2[2] = {zero, zero};
  ushort8 c0a, c0b, c1a, c1b;      // con prefetch (2-deep)
  ushort8 w0a, w0b, w1a, w1b;      // w1mF prefetch (1-step-ahead of its ds_write)

  // -------- prologue: stage A(0), B(0); prefetch con(1), B(1) --------
  {
    ushort8 ca = *reinterpret_cast<const ushort8*>(conA_base);
    ushort8 cb = *reinterpret_cast<const ushort8*>(conB_base);
    ushort8 wa = *reinterpret_cast<const ushort8*>(w1A_base);          // B(hc=0,kc=0)
    ushort8 wb = *reinterpret_cast<const ushort8*>(w1B_base);
    floatx4 av0 = *reinterpret_cast<const floatx4*>(&a_row[gkoff]);
    floatx4 av1 = *reinterpret_cast<const floatx4*>(&a_row[gkoff + 4]);
    uint4v dA, dB;
    dA[0]=pack2(av0[0]*b2f(ca[0]), av0[1]*b2f(ca[1])); dA[1]=pack2(av0[2]*b2f(ca[2]), av0[3]*b2f(ca[3]));
    dA[2]=pack2(av1[0]*b2f(ca[4]), av1[1]*b2f(ca[5])); dA[3]=pack2(av1[2]*b2f(ca[6]), av1[3]*b2f(ca[7]));
    dB[0]=pack2(av0[0]*b2f(cb[0]), av0[1]*b2f(cb[1])); dB[1]=pack2(av0[2]*b2f(cb[2]), av0[3]*b2f(cb[3]));
    dB[2]=pack2(av1[0]*b2f(cb[4]), av1[1]*b2f(cb[5])); dB[3]=pack2(av1[2]*b2f(cb[6]), av1[3]*b2f(cb[7]));
    *reinterpret_cast<uint4v*>(&A_lds[0][jt0][ln0][0]) = dA;
    *reinterpret_cast<uint4v*>(&A_lds[0][jt1][ln0][0]) = dB;
    *reinterpret_cast<ushort8*>(&B_lds[0][jt0][ln0][0]) = wa;
    *reinterpret_cast<ushort8*>(&B_lds[0][jt1][ln0][0]) = wb;
    c0a = *reinterpret_cast<const ushort8*>(conA_base + 32);           // con(kc=1)
    c0b = *reinterpret_cast<const ushort8*>(conB_base + 32);
    w0a = *reinterpret_cast<const ushort8*>(w1A_base + 512);           // B(hc=0,kc=1)
    w0b = *reinterpret_cast<const ushort8*>(w1B_base + 512);
  }
  __syncthreads();

// KSTEP(kc): MFMA on buffer cur=kc&1; write A(kc+1),B(kc+1) to nxt; prefetch
// con(kc+2) and B(kc+2) into regs (B index advances into next hc at kc>=22).
#define KSTEP(KC, CURA, CURB, NXTA, NXTB, WCA, WCB, WNA, WNB)                          \
{                                                                                      \
  const int kc = (KC);                                                                 \
  const int cur = kc & 1, nxt = cur ^ 1;                                               \
  const int kc1 = (kc + 1) % 24;                                                       \
  const int kc2 = (kc + 2) % 24;                                                       \
  const int hc2 = hc + ((kc >= 22) ? 1 : 0);                                           \
  NXTA = *reinterpret_cast<const ushort8*>(conA_base + kc2*32);                        \
  NXTB = *reinterpret_cast<const ushort8*>(conB_base + kc2*32);                        \
  WNA = *reinterpret_cast<const ushort8*>(w1A_base + (((size_t)(hc2*8)*24 + kc2) << 9)); \
  WNB = *reinterpret_cast<const ushort8*>(w1B_base + (((size_t)(hc2*8)*24 + kc2) << 9)); \
  {                                                                                    \
    short8 af[4], bfr[4];                                                              \
    _Pragma("unroll")                                                                  \
    for (int m = 0; m < 4; ++m) af[m] = *reinterpret_cast<const short8*>(&A_lds[cur][wr*4+m][lane][0]); \
    _Pragma("unroll")                                                                  \
    for (int n = 0; n < 4; ++n) bfr[n] = *reinterpret_cast<const short8*>(&B_lds[cur][wcq*4+n][lane][0]); \
    _Pragma("unroll")                                                                  \
    for (int m = 0; m < 4; ++m)                                                        \
      _Pragma("unroll")                                                                \
      for (int n = 0; n < 4; ++n)                                                      \
        acc[m][n] = __builtin_amdgcn_mfma_f32_16x16x32_bf16(af[m], bfr[n], acc[m][n], 0,0,0); \
  }                                                                                    \
  {                                                                                    \
    floatx4 av0 = *reinterpret_cast<const floatx4*>(&a_row[kc1*32 + gkoff]);           \
    floatx4 av1 = *reinterpret_cast<const floatx4*>(&a_row[kc1*32 + gkoff + 4]);       \
    uint4v dA, dB;                                                                     \
    dA[0]=pack2(av0[0]*b2f(CURA[0]), av0[1]*b2f(CURA[1]));                             \
    dA[1]=pack2(av0[2]*b2f(CURA[2]), av0[3]*b2f(CURA[3]));                             \
    dA[2]=pack2(av1[0]*b2f(CURA[4]), av1[1]*b2f(CURA[5]));                             \
    dA[3]=pack2(av1[2]*b2f(CURA[6]), av1[3]*b2f(CURA[7]));                             \
    dB[0]=pack2(av0[0]*b2f(CURB[0]), av0[1]*b2f(CURB[1]));                             \
    dB[1]=pack2(av0[2]*b2f(CURB[2]), av0[3]*b2f(CURB[3]));                             \
    dB[2]=pack2(av1[0]*b2f(CURB[4]), av1[1]*b2f(CURB[5]));                             \
    dB[3]=pack2(av1[2]*b2f(CURB[6]), av1[3]*b2f(CURB[7]));                             \
    *reinterpret_cast<uint4v*>(&A_lds[nxt][jt0][ln0][0]) = dA;                         \
    *reinterpret_cast<uint4v*>(&A_lds[nxt][jt1][ln0][0]) = dB;                         \
    *reinterpret_cast<ushort8*>(&B_lds[nxt][jt0][ln0][0]) = WCA;                       \
    *reinterpret_cast<ushort8*>(&B_lds[nxt][jt1][ln0][0]) = WCB;                       \
  }                                                                                    \
  __syncthreads();                                                                     \
}

  for (int hc = 0; hc < 8; ++hc) {
    floatx4 acc[4][4];
    #pragma unroll
    for (int m = 0; m < 4; ++m)
      #pragma unroll
      for (int n = 0; n < 4; ++n) acc[m][n] = zero;

    #pragma unroll
    for (int kcp = 0; kcp < 12; ++kcp) {
      KSTEP(2*kcp,     c0a, c0b, c1a, c1b, w0a, w0b, w1a, w1b);
      KSTEP(2*kcp + 1, c1a, c1b, c0a, c0b, w1a, w1b, w0a, w0b);
    }

    // -------- epilogue: W2 stage + tanh + hidF + GEMM2 --------
    {
      int ksW = t >> 6, lnW = t & 63, colW = lnW & 15, sW = lnW >> 4;
      const float* w2p = W2 + (size_t)(hc*128 + ksW*4 + sW)*Lc + colW;
      uint4v dW;
      dW[0] = pack2(w2p[0],     w2p[256]);
      dW[1] = pack2(w2p[2*256], w2p[3*256]);
      dW[2] = pack2(w2p[4*256], w2p[5*256]);
      dW[3] = pack2(w2p[6*256], w2p[7*256]);
      *reinterpret_cast<uint4v*>(&W2_lds[ksW][lnW][0]) = dW;
    }
    float pb[4];
    #pragma unroll
    for (int n = 0; n < 4; ++n) {
      int gh = hc*128 + wcq*64 + n*16 + colh;
      pb[n] = P[(size_t)(bN + i)*HIDc + gh] + b1[gh];
    }
    int ks_h = colh >> 2;
    unsigned swz = (unsigned)(colh & 7) << 4;
    #pragma unroll
    for (int m = 0; m < 4; ++m) {
      int jt = wr*4 + m;
      #pragma unroll
      for (int r = 0; r < 4; ++r) {
        int jl = wr*64 + m*16 + rbase + r;
        const float* qp = Q + (size_t)(bN + jl)*HIDc + hc*128 + wcq*64 + colh;
        float v0 = acc[m][0][r] + pb[0] + qp[0];
        float v1 = acc[m][1][r] + pb[1] + qp[16];
        float v2 = acc[m][2][r] + pb[2] + qp[32];
        float v3 = acc[m][3][r] + pb[3] + qp[48];
        unsigned lo = pack2(tanh_fast(v0), tanh_fast(v1));
        unsigned hi = pack2(tanh_fast(v2), tanh_fast(v3));
        int lnH = (rbase + r) | ((colh & 3) << 4);
        unsigned off = ((unsigned)(((jt*4 + ks_h)*64 + lnH)*16 + 8*wcq)) ^ swz;
        uint2v dv = { lo, hi };
        *reinterpret_cast<uint2v*>(hidb + off) = dv;
      }
    }
    __syncthreads();
    #pragma unroll
    for (int jt2 = 0; jt2 < 2; ++jt2) {
      int jt = w*2 + jt2;
      #pragma unroll
      for (int ks = 0; ks < 4; ++ks) {
        unsigned key = (unsigned)((ks*4 + (lane >> 4)) & 7) << 4;
        unsigned roff = ((unsigned)(((jt*4 + ks)*64 + lane)*16)) ^ key;
        short8 a2  = *reinterpret_cast<const short8*>(hidb + roff);
        short8 b2v = *reinterpret_cast<const short8*>(&W2_lds[ks][lane][0]);
        acc2[jt2] = __builtin_amdgcn_mfma_f32_16x16x32_bf16(a2, b2v, acc2[jt2], 0,0,0);
      }
    }
    __syncthreads();
  }
#undef KSTEP

  float bl = b2[colh];
  #pragma unroll
  for (int jt2 = 0; jt2 < 2; ++jt2) {
    int jt = w*2 + jt2;
    #pragma unroll
    for (int r = 0; r < 4; ++r) {
      int jl = jt*16 + rbase + r;
      out[((size_t)bi*Nc + jl)*Lc + colh] = acc2[jt2][r] + bl;
    }
  }
}

extern "C" void kernel_launch(void* const* d_in, const int* in_sizes, int n_in,
                              void* d_out, int out_size, void* d_ws, size_t ws_size,
                              hipStream_t stream) {
  const float* AH = (const float*)d_in[0];
  const int*   ST = (const int*)d_in[1];
  const float* W1 = (const float*)d_in[2];
  const float* b1 = (const float*)d_in[3];
  const float* W2 = (const float*)d_in[4];
  const float* b2 = (const float*)d_in[5];
  float* out = (float*)d_out;

  char* ws = (char*)d_ws;
  unsigned short* con  = (unsigned short*)ws;                //   786,432 B
  unsigned short* w1mF = (unsigned short*)(ws +   786432);   // 1,572,864 B
  unsigned short* wPQF = (unsigned short*)(ws +  2359296);   // 3,145,728 B
  float* P = (float*)(ws + 5505024);                         // 2,097,152 B
  float* Q = (float*)(ws + 7602176);                         // 2,097,152 B

  k_gather<<<512, 256, 0, stream>>>(AH, ST, con);
  k_w1m<<<384, 256, 0, stream>>>(W1, w1mF);
  k_wpq<<<768, 256, 0, stream>>>(W1, wPQF);
  k_pq<<<256, 256, 0, stream>>>(con, wPQF, P, Q);
  k_main<<<512, 256, 0, stream>>>(con, w1mF, P, Q, b1, W2, b2, out);
}

// Round 4
// 348.668 us; speedup vs baseline: 1.9239x; 1.5763x over previous
//
#include <hip/hip_runtime.h>
#include <hip/hip_bf16.h>

typedef __attribute__((ext_vector_type(8))) short short8;
typedef __attribute__((ext_vector_type(8))) unsigned short ushort8;
typedef __attribute__((ext_vector_type(4))) float floatx4;
typedef __attribute__((ext_vector_type(4))) unsigned int uint4v;
typedef __attribute__((ext_vector_type(2))) unsigned int uint2v;

#define DEVINL static __device__ __forceinline__

DEVINL float b2f(unsigned short s){ union{unsigned u; float f;} v; v.u=((unsigned)s)<<16; return v.f; }
DEVINL unsigned fbits(float f){ union{float f; unsigned u;} v; v.f=f; return v.u; }
// pack two floats to bf16 pair (f0 -> low16, f1 -> high16), round-half-up via +0x8000
DEVINL unsigned pack2(float f0, float f1){
  return __builtin_amdgcn_perm(fbits(f1)+0x8000u, fbits(f0)+0x8000u, 0x07060302u);
}
DEVINL float tanh_fast(float v){
  float ax = fabsf(v);
  float ex = __expf(-2.f*ax);
  float th = (1.f - ex)*__builtin_amdgcn_rcpf(1.f + ex);
  return copysignf(th, v);
}

constexpr int Sc=256, Hc=768, Nc=128, HIDc=1024, Lc=16;

// ---------------- gather + bf16 cast: con[b*N+n][768] ----------------
__global__ __launch_bounds__(256) void k_gather(const float* __restrict__ AH,
                                                const int* __restrict__ ST,
                                                unsigned short* __restrict__ con){
  int row = blockIdx.x;            // b*128 + n
  int b = row >> 7;
  int st = ST[row];
  const float* src = AH + ((size_t)(b*Sc + st))*Hc;
  unsigned short* dst = con + (size_t)row*Hc;
  int t = threadIdx.x;
  if (t < 192) {
    float4 v = reinterpret_cast<const float4*>(src)[t];
    uint2v o = { pack2(v.x, v.y), pack2(v.z, v.w) };
    *reinterpret_cast<uint2v*>(dst + 4*t) = o;
  }
}

// ---------- W1m (rows 2304..3071 of W1) -> bf16 fragments, coalesced ----------
// layout: [htg(64)][kc(24)][lane(64)][e(8)], lane = col | (seg<<4), k = kc*32+seg*8+e
__global__ __launch_bounds__(256) void k_w1m(const float* __restrict__ W1,
                                             unsigned short* __restrict__ w1mF){
  int sid = blockIdx.x*256 + threadIdx.x;     // 0..98303
  int lane = sid & 63, kcq = (sid >> 6) % 24, htg = sid / (24*64);
  int col = lane & 15, seg = lane >> 4;
  int h = (htg >> 3)*128 + (htg & 7)*16 + col;
  const float* wp = W1 + (size_t)(2304 + kcq*32 + seg*8)*1024 + h;
  uint4v d;
  d[0] = pack2(wp[0],      wp[1024]);
  d[1] = pack2(wp[2*1024], wp[3*1024]);
  d[2] = pack2(wp[4*1024], wp[5*1024]);
  d[3] = pack2(wp[6*1024], wp[7*1024]);
  *reinterpret_cast<uint4v*>(w1mF + (size_t)sid*8) = d;
}

// ---------- combined P/Q weights -> bf16 fragments ----------
// wPQF: [ht(128)][kc(24)][lane(64)][e(8)]; h'<1024: W1[k][h]+W1[1536+k][h]; else W1[768+k][h]-W1[1536+k][h]
__global__ __launch_bounds__(256) void k_wpq(const float* __restrict__ W1,
                                             unsigned short* __restrict__ wPQF){
  int sid = blockIdx.x*256 + threadIdx.x;     // 0..196607
  int lane = sid & 63, kcq = (sid >> 6) % 24, ht = sid / (24*64);
  int col = lane & 15, seg = lane >> 4;
  int hp = ht*16 + col;
  int kb = kcq*32 + seg*8;
  uint4v d;
  if (hp < 1024) {
    const float* w0 = W1 + (size_t)kb*1024 + hp;
    const float* wd = W1 + (size_t)(1536+kb)*1024 + hp;
    d[0] = pack2(w0[0]+wd[0],           w0[1024]+wd[1024]);
    d[1] = pack2(w0[2*1024]+wd[2*1024], w0[3*1024]+wd[3*1024]);
    d[2] = pack2(w0[4*1024]+wd[4*1024], w0[5*1024]+wd[5*1024]);
    d[3] = pack2(w0[6*1024]+wd[6*1024], w0[7*1024]+wd[7*1024]);
  } else {
    int hq = hp - 1024;
    const float* wc = W1 + (size_t)(768+kb)*1024 + hq;
    const float* wd = W1 + (size_t)(1536+kb)*1024 + hq;
    d[0] = pack2(wc[0]-wd[0],           wc[1024]-wd[1024]);
    d[1] = pack2(wc[2*1024]-wd[2*1024], wc[3*1024]-wd[3*1024]);
    d[2] = pack2(wc[4*1024]-wd[4*1024], wc[5*1024]-wd[5*1024]);
    d[3] = pack2(wc[6*1024]-wd[6*1024], wc[7*1024]-wd[7*1024]);
  }
  *reinterpret_cast<uint4v*>(wPQF + (size_t)sid*8) = d;
}

// ---------------- P/Q via MFMA: out[512 rows][2048 cols] ----------------
__global__ __launch_bounds__(256) void k_pq(const unsigned short* __restrict__ con,
                                            const unsigned short* __restrict__ wPQF,
                                            float* __restrict__ P, float* __restrict__ Q){
  int rg = blockIdx.x >> 4, hg = blockIdx.x & 15;     // 16 rowgroups x 16 colgroups
  int t = threadIdx.x, w = t >> 6, lane = t & 63;
  int colh = lane & 15, rseg = lane >> 4;
  floatx4 zero = {0.f,0.f,0.f,0.f};
  floatx4 acc[2][2] = {{zero,zero},{zero,zero}};
  const unsigned short* a0p = con + (size_t)(rg*32 + colh)*Hc + rseg*8;
  const unsigned short* a1p = a0p + 16*Hc;
  const unsigned short* b0p = wPQF + (((size_t)((hg*8 + w*2)*24)) << 9) + (lane << 3);
  const unsigned short* b1p = b0p + (24 << 9);
  #pragma unroll
  for (int kc = 0; kc < 24; ++kc) {
    short8 af0 = *reinterpret_cast<const short8*>(a0p + kc*32);
    short8 af1 = *reinterpret_cast<const short8*>(a1p + kc*32);
    short8 bf0 = *reinterpret_cast<const short8*>(b0p + ((size_t)kc << 9));
    short8 bf1 = *reinterpret_cast<const short8*>(b1p + ((size_t)kc << 9));
    acc[0][0] = __builtin_amdgcn_mfma_f32_16x16x32_bf16(af0, bf0, acc[0][0], 0,0,0);
    acc[0][1] = __builtin_amdgcn_mfma_f32_16x16x32_bf16(af0, bf1, acc[0][1], 0,0,0);
    acc[1][0] = __builtin_amdgcn_mfma_f32_16x16x32_bf16(af1, bf0, acc[1][0], 0,0,0);
    acc[1][1] = __builtin_amdgcn_mfma_f32_16x16x32_bf16(af1, bf1, acc[1][1], 0,0,0);
  }
  #pragma unroll
  for (int m = 0; m < 2; ++m)
    #pragma unroll
    for (int n = 0; n < 2; ++n)
      #pragma unroll
      for (int rr = 0; rr < 4; ++rr) {
        int row = rg*32 + m*16 + rseg*4 + rr;
        int hp = hg*128 + w*32 + n*16 + colh;
        float val = acc[m][n][rr];
        if (hg < 8) P[(size_t)row*HIDc + hp] = val;
        else        Q[(size_t)row*HIDc + (hp - 1024)] = val;
      }
}

// ---------------- fused main kernel: one block per (b,i) ----------------
// r1 memory structure (single-buffered LDS, 2 barriers/K-step, plain vector
// loads, no deep prefetch -- the pattern that achieved 18.8MB FETCH) with:
//  - A/B LDS unioned with hidF (never live simultaneously): 56.3KB -> 39.9KB
//    => 4 blocks/CU (double r1's occupancy, the actual r1 limiter)
//  - pack2 bf16 packing (fewer VALU than r1's scalar f2b)
//  - r3's swizzled hidF epilogue + b64 writes (numerics-proven)
__global__ __launch_bounds__(256, 4) void k_main(const unsigned short* __restrict__ con,
    const unsigned short* __restrict__ w1mF,
    const float* __restrict__ P, const float* __restrict__ Q, const float* __restrict__ b1,
    const float* __restrict__ W2, const float* __restrict__ b2, float* __restrict__ out){
  __shared__ __align__(16) char Xbuf[32768];     // union: A(8K)+B(8K) | hidF(32K)
  __shared__ float a_row[768];
  __shared__ unsigned short W2_lds[4][64][8];

  typedef unsigned short lds_tile[64][8];
  lds_tile* A_lds = reinterpret_cast<lds_tile*>(Xbuf);          // [8][64][8]
  lds_tile* B_lds = reinterpret_cast<lds_tile*>(Xbuf + 8192);   // [8][64][8]
  char* hidb = Xbuf;                                            // [8][4][64][8]

  int bi = blockIdx.x;                 // b*128 + i
  int b = bi >> 7, i = bi & 127;
  int t = threadIdx.x, w = t >> 6, lane = t & 63;
  int wr = w >> 1, wcq = w & 1;        // 2x2 wave grid
  int bN = b * Nc;
  int colh = lane & 15, rbase = (lane >> 4) << 2;

  // per-thread staging invariants (thread stages slots jt0 and jt1 at ln0)
  int jt0 = t >> 6, ln0 = t & 63;
  int jt1 = jt0 + 4;
  int jA = (jt0 << 4) | (t & 15);
  int gkoff = ((t >> 4) & 3) << 3;
  const unsigned short* conA_base = con + (size_t)(bN + jA)*Hc + gkoff;
  const unsigned short* conB_base = conA_base + (size_t)64*Hc;
  const unsigned short* w1A_base = w1mF + ((size_t)jt0*24 << 9) + (ln0 << 3);
  const unsigned short* w1B_base = w1mF + ((size_t)jt1*24 << 9) + (ln0 << 3);

  for (int k = t; k < 768; k += 256) a_row[k] = b2f(con[(size_t)(bN + i)*Hc + k]);

  floatx4 zero = {0.f,0.f,0.f,0.f};
  floatx4 acc2[2] = {zero, zero};
  __syncthreads();

  for (int hc = 0; hc < 8; ++hc) {
    floatx4 acc[4][4];
    #pragma unroll
    for (int m = 0; m < 4; ++m)
      #pragma unroll
      for (int n = 0; n < 4; ++n) acc[m][n] = zero;

    for (int kc = 0; kc < 24; ++kc) {
      int k0 = kc << 5;
      // ---- stage A (product) and B (w1m fragments) ----
      {
        ushort8 ca = *reinterpret_cast<const ushort8*>(conA_base + k0);
        ushort8 cb = *reinterpret_cast<const ushort8*>(conB_base + k0);
        ushort8 wa = *reinterpret_cast<const ushort8*>(w1A_base + (((size_t)(hc*8)*24 + kc) << 9));
        ushort8 wb = *reinterpret_cast<const ushort8*>(w1B_base + (((size_t)(hc*8)*24 + kc) << 9));
        floatx4 av0 = *reinterpret_cast<const floatx4*>(&a_row[k0 + gkoff]);
        floatx4 av1 = *reinterpret_cast<const floatx4*>(&a_row[k0 + gkoff + 4]);
        uint4v dA, dB;
        dA[0]=pack2(av0[0]*b2f(ca[0]), av0[1]*b2f(ca[1])); dA[1]=pack2(av0[2]*b2f(ca[2]), av0[3]*b2f(ca[3]));
        dA[2]=pack2(av1[0]*b2f(ca[4]), av1[1]*b2f(ca[5])); dA[3]=pack2(av1[2]*b2f(ca[6]), av1[3]*b2f(ca[7]));
        dB[0]=pack2(av0[0]*b2f(cb[0]), av0[1]*b2f(cb[1])); dB[1]=pack2(av0[2]*b2f(cb[2]), av0[3]*b2f(cb[3]));
        dB[2]=pack2(av1[0]*b2f(cb[4]), av1[1]*b2f(cb[5])); dB[3]=pack2(av1[2]*b2f(cb[6]), av1[3]*b2f(cb[7]));
        *reinterpret_cast<uint4v*>(&A_lds[jt0][ln0][0]) = dA;
        *reinterpret_cast<uint4v*>(&A_lds[jt1][ln0][0]) = dB;
        *reinterpret_cast<ushort8*>(&B_lds[jt0][ln0][0]) = wa;
        *reinterpret_cast<ushort8*>(&B_lds[jt1][ln0][0]) = wb;
      }
      __syncthreads();
      {
        short8 af[4], bfr[4];
        #pragma unroll
        for (int m = 0; m < 4; ++m) af[m] = *reinterpret_cast<const short8*>(&A_lds[wr*4+m][lane][0]);
        #pragma unroll
        for (int n = 0; n < 4; ++n) bfr[n] = *reinterpret_cast<const short8*>(&B_lds[wcq*4+n][lane][0]);
        #pragma unroll
        for (int m = 0; m < 4; ++m)
          #pragma unroll
          for (int n = 0; n < 4; ++n)
            acc[m][n] = __builtin_amdgcn_mfma_f32_16x16x32_bf16(af[m], bfr[n], acc[m][n], 0,0,0);
      }
      __syncthreads();
    }

    // -------- epilogue: W2 stage + tanh + hidF (into union) + GEMM2 --------
    {
      int ksW = t >> 6, lnW = t & 63, colW = lnW & 15, sW = lnW >> 4;
      const float* w2p = W2 + (size_t)(hc*128 + ksW*4 + sW)*Lc + colW;
      uint4v dW;
      dW[0] = pack2(w2p[0],     w2p[256]);
      dW[1] = pack2(w2p[2*256], w2p[3*256]);
      dW[2] = pack2(w2p[4*256], w2p[5*256]);
      dW[3] = pack2(w2p[6*256], w2p[7*256]);
      *reinterpret_cast<uint4v*>(&W2_lds[ksW][lnW][0]) = dW;
    }
    float pb[4];
    #pragma unroll
    for (int n = 0; n < 4; ++n) {
      int gh = hc*128 + wcq*64 + n*16 + colh;
      pb[n] = P[(size_t)(bN + i)*HIDc + gh] + b1[gh];
    }
    int ks_h = colh >> 2;
    unsigned swz = (unsigned)(colh & 7) << 4;
    #pragma unroll
    for (int m = 0; m < 4; ++m) {
      int jt = wr*4 + m;
      #pragma unroll
      for (int r = 0; r < 4; ++r) {
        int jl = wr*64 + m*16 + rbase + r;
        const float* qp = Q + (size_t)(bN + jl)*HIDc + hc*128 + wcq*64 + colh;
        float v0 = acc[m][0][r] + pb[0] + qp[0];
        float v1 = acc[m][1][r] + pb[1] + qp[16];
        float v2 = acc[m][2][r] + pb[2] + qp[32];
        float v3 = acc[m][3][r] + pb[3] + qp[48];
        unsigned lo = pack2(tanh_fast(v0), tanh_fast(v1));
        unsigned hi = pack2(tanh_fast(v2), tanh_fast(v3));
        int lnH = (rbase + r) | ((colh & 3) << 4);
        unsigned off = ((unsigned)(((jt*4 + ks_h)*64 + lnH)*16 + 8*wcq)) ^ swz;
        uint2v dv = { lo, hi };
        *reinterpret_cast<uint2v*>(hidb + off) = dv;
      }
    }
    __syncthreads();
    #pragma unroll
    for (int jt2 = 0; jt2 < 2; ++jt2) {
      int jt = w*2 + jt2;
      #pragma unroll
      for (int ks = 0; ks < 4; ++ks) {
        unsigned key = (unsigned)((ks*4 + (lane >> 4)) & 7) << 4;
        unsigned roff = ((unsigned)(((jt*4 + ks)*64 + lane)*16)) ^ key;
        short8 a2  = *reinterpret_cast<const short8*>(hidb + roff);
        short8 b2v = *reinterpret_cast<const short8*>(&W2_lds[ks][lane][0]);
        acc2[jt2] = __builtin_amdgcn_mfma_f32_16x16x32_bf16(a2, b2v, acc2[jt2], 0,0,0);
      }
    }
    __syncthreads();
  }

  float bl = b2[colh];
  #pragma unroll
  for (int jt2 = 0; jt2 < 2; ++jt2) {
    int jt = w*2 + jt2;
    #pragma unroll
    for (int r = 0; r < 4; ++r) {
      int jl = jt*16 + rbase + r;
      out[((size_t)bi*Nc + jl)*Lc + colh] = acc2[jt2][r] + bl;
    }
  }
}

extern "C" void kernel_launch(void* const* d_in, const int* in_sizes, int n_in,
                              void* d_out, int out_size, void* d_ws, size_t ws_size,
                              hipStream_t stream) {
  const float* AH = (const float*)d_in[0];
  const int*   ST = (const int*)d_in[1];
  const float* W1 = (const float*)d_in[2];
  const float* b1 = (const float*)d_in[3];
  const float* W2 = (const float*)d_in[4];
  const float* b2 = (const float*)d_in[5];
  float* out = (float*)d_out;

  char* ws = (char*)d_ws;
  unsigned short* con  = (unsigned short*)ws;                //   786,432 B
  unsigned short* w1mF = (unsigned short*)(ws +   786432);   // 1,572,864 B
  unsigned short* wPQF = (unsigned short*)(ws +  2359296);   // 3,145,728 B
  float* P = (float*)(ws + 5505024);                         // 2,097,152 B
  float* Q = (float*)(ws + 7602176);                         // 2,097,152 B

  k_gather<<<512, 256, 0, stream>>>(AH, ST, con);
  k_w1m<<<384, 256, 0, stream>>>(W1, w1mF);
  k_wpq<<<768, 256, 0, stream>>>(W1, wPQF);
  k_pq<<<256, 256, 0, stream>>>(con, wPQF, P, Q);
  k_main<<<512, 256, 0, stream>>>(con, w1mF, P, Q, b1, W2, b2, out);
}

// Round 5
// 208.796 us; speedup vs baseline: 3.2127x; 1.6699x over previous
//
#include <hip/hip_runtime.h>
#include <hip/hip_bf16.h>

typedef __attribute__((ext_vector_type(8))) short short8;
typedef __attribute__((ext_vector_type(8))) unsigned short ushort8;
typedef __attribute__((ext_vector_type(4))) float floatx4;
typedef __attribute__((ext_vector_type(4))) unsigned int uint4v;
typedef __attribute__((ext_vector_type(2))) unsigned int uint2v;

#define DEVINL static __device__ __forceinline__

DEVINL float b2f(unsigned short s){ union{unsigned u; float f;} v; v.u=((unsigned)s)<<16; return v.f; }
DEVINL unsigned fbits(float f){ union{float f; unsigned u;} v; v.f=f; return v.u; }
// pack two floats to bf16 pair (f0 -> low16, f1 -> high16), round-half-up via +0x8000
DEVINL unsigned pack2(float f0, float f1){
  return __builtin_amdgcn_perm(fbits(f1)+0x8000u, fbits(f0)+0x8000u, 0x07060302u);
}
DEVINL float tanh_fast(float v){
  float ax = fabsf(v);
  float ex = __expf(-2.f*ax);
  float th = (1.f - ex)*__builtin_amdgcn_rcpf(1.f + ex);
  return copysignf(th, v);
}

constexpr int Sc=256, Hc=768, Nc=128, HIDc=1024, Lc=16;

// ---------------- gather + bf16 cast: con[b*N+n][768] ----------------
__global__ __launch_bounds__(256) void k_gather(const float* __restrict__ AH,
                                                const int* __restrict__ ST,
                                                unsigned short* __restrict__ con){
  int row = blockIdx.x;            // b*128 + n
  int b = row >> 7;
  int st = ST[row];
  const float* src = AH + ((size_t)(b*Sc + st))*Hc;
  unsigned short* dst = con + (size_t)row*Hc;
  int t = threadIdx.x;
  if (t < 192) {
    float4 v = reinterpret_cast<const float4*>(src)[t];
    uint2v o = { pack2(v.x, v.y), pack2(v.z, v.w) };
    *reinterpret_cast<uint2v*>(dst + 4*t) = o;
  }
}

// ---------- W1m (rows 2304..3071 of W1) -> bf16 fragments, coalesced ----------
// layout: [htg(64)][kc(24)][lane(64)][e(8)], lane = col | (seg<<4), k = kc*32+seg*8+e
__global__ __launch_bounds__(256) void k_w1m(const float* __restrict__ W1,
                                             unsigned short* __restrict__ w1mF){
  int sid = blockIdx.x*256 + threadIdx.x;     // 0..98303
  int lane = sid & 63, kcq = (sid >> 6) % 24, htg = sid / (24*64);
  int col = lane & 15, seg = lane >> 4;
  int h = (htg >> 3)*128 + (htg & 7)*16 + col;
  const float* wp = W1 + (size_t)(2304 + kcq*32 + seg*8)*1024 + h;
  uint4v d;
  d[0] = pack2(wp[0],      wp[1024]);
  d[1] = pack2(wp[2*1024], wp[3*1024]);
  d[2] = pack2(wp[4*1024], wp[5*1024]);
  d[3] = pack2(wp[6*1024], wp[7*1024]);
  *reinterpret_cast<uint4v*>(w1mF + (size_t)sid*8) = d;
}

// ---------- combined P/Q weights -> bf16 fragments ----------
// wPQF: [ht(128)][kc(24)][lane(64)][e(8)]; h'<1024: W1[k][h]+W1[1536+k][h]; else W1[768+k][h]-W1[1536+k][h]
__global__ __launch_bounds__(256) void k_wpq(const float* __restrict__ W1,
                                             unsigned short* __restrict__ wPQF){
  int sid = blockIdx.x*256 + threadIdx.x;     // 0..196607
  int lane = sid & 63, kcq = (sid >> 6) % 24, ht = sid / (24*64);
  int col = lane & 15, seg = lane >> 4;
  int hp = ht*16 + col;
  int kb = kcq*32 + seg*8;
  uint4v d;
  if (hp < 1024) {
    const float* w0 = W1 + (size_t)kb*1024 + hp;
    const float* wd = W1 + (size_t)(1536+kb)*1024 + hp;
    d[0] = pack2(w0[0]+wd[0],           w0[1024]+wd[1024]);
    d[1] = pack2(w0[2*1024]+wd[2*1024], w0[3*1024]+wd[3*1024]);
    d[2] = pack2(w0[4*1024]+wd[4*1024], w0[5*1024]+wd[5*1024]);
    d[3] = pack2(w0[6*1024]+wd[6*1024], w0[7*1024]+wd[7*1024]);
  } else {
    int hq = hp - 1024;
    const float* wc = W1 + (size_t)(768+kb)*1024 + hq;
    const float* wd = W1 + (size_t)(1536+kb)*1024 + hq;
    d[0] = pack2(wc[0]-wd[0],           wc[1024]-wd[1024]);
    d[1] = pack2(wc[2*1024]-wd[2*1024], wc[3*1024]-wd[3*1024]);
    d[2] = pack2(wc[4*1024]-wd[4*1024], wc[5*1024]-wd[5*1024]);
    d[3] = pack2(wc[6*1024]-wd[6*1024], wc[7*1024]-wd[7*1024]);
  }
  *reinterpret_cast<uint4v*>(wPQF + (size_t)sid*8) = d;
}

// ---------------- P/Q via MFMA: out[512 rows][2048 cols] ----------------
__global__ __launch_bounds__(256) void k_pq(const unsigned short* __restrict__ con,
                                            const unsigned short* __restrict__ wPQF,
                                            float* __restrict__ P, float* __restrict__ Q){
  int rg = blockIdx.x >> 4, hg = blockIdx.x & 15;     // 16 rowgroups x 16 colgroups
  int t = threadIdx.x, w = t >> 6, lane = t & 63;
  int colh = lane & 15, rseg = lane >> 4;
  floatx4 zero = {0.f,0.f,0.f,0.f};
  floatx4 acc[2][2] = {{zero,zero},{zero,zero}};
  const unsigned short* a0p = con + (size_t)(rg*32 + colh)*Hc + rseg*8;
  const unsigned short* a1p = a0p + 16*Hc;
  const unsigned short* b0p = wPQF + (((size_t)((hg*8 + w*2)*24)) << 9) + (lane << 3);
  const unsigned short* b1p = b0p + (24 << 9);
  #pragma unroll
  for (int kc = 0; kc < 24; ++kc) {
    short8 af0 = *reinterpret_cast<const short8*>(a0p + kc*32);
    short8 af1 = *reinterpret_cast<const short8*>(a1p + kc*32);
    short8 bf0 = *reinterpret_cast<const short8*>(b0p + ((size_t)kc << 9));
    short8 bf1 = *reinterpret_cast<const short8*>(b1p + ((size_t)kc << 9));
    acc[0][0] = __builtin_amdgcn_mfma_f32_16x16x32_bf16(af0, bf0, acc[0][0], 0,0,0);
    acc[0][1] = __builtin_amdgcn_mfma_f32_16x16x32_bf16(af0, bf1, acc[0][1], 0,0,0);
    acc[1][0] = __builtin_amdgcn_mfma_f32_16x16x32_bf16(af1, bf0, acc[1][0], 0,0,0);
    acc[1][1] = __builtin_amdgcn_mfma_f32_16x16x32_bf16(af1, bf1, acc[1][1], 0,0,0);
  }
  #pragma unroll
  for (int m = 0; m < 2; ++m)
    #pragma unroll
    for (int n = 0; n < 2; ++n)
      #pragma unroll
      for (int rr = 0; rr < 4; ++rr) {
        int row = rg*32 + m*16 + rseg*4 + rr;
        int hp = hg*128 + w*32 + n*16 + colh;
        float val = acc[m][n][rr];
        if (hg < 8) P[(size_t)row*HIDc + hp] = val;
        else        Q[(size_t)row*HIDc + (hp - 1024)] = val;
      }
}

// ---------------- fused main kernel: one block per (b,i,jhalf) ----------------
// 1024 blocks (4/CU). Each block: 64 j-rows x 1024 h. 4 waves, wave w owns
// j-tile w (16 rows), all 8 h-tiles -> acc[8] (32 VGPR). r1-proven 2-barrier
// K-loop, plain vector loads. GEMM2 uses a custom self-consistent k-mapping
// (ks=colh>>2, kseg=colh&3, e=n) so tanh output is ONE 16B LDS write/row,
// XOR-swizzled by colh&7 (same formula on read).
__global__ __launch_bounds__(256, 4) void k_main(const unsigned short* __restrict__ con,
    const unsigned short* __restrict__ w1mF,
    const float* __restrict__ P, const float* __restrict__ Q, const float* __restrict__ b1,
    const float* __restrict__ W2, const float* __restrict__ b2, float* __restrict__ out){
  __shared__ __align__(16) char Xbuf[16384];     // union: A(4K)+B(8K) | hidF(16K)
  __shared__ float a_row[768];
  __shared__ float Pi_lds[1024];
  __shared__ unsigned short W2_lds[4][64][8];

  typedef unsigned short lds_tile[64][8];
  lds_tile* A_lds = reinterpret_cast<lds_tile*>(Xbuf);          // [4][64][8]
  lds_tile* B_lds = reinterpret_cast<lds_tile*>(Xbuf + 4096);   // [8][64][8]
  char* hidb = Xbuf;                                            // [4][4][64][8] swizzled

  int bid = blockIdx.x;
  int jh = bid & 1, bi = bid >> 1;     // bi = b*128 + i
  int b = bi >> 7, i = bi & 127;
  int t = threadIdx.x, w = t >> 6, lane = t & 63;
  int bN = b * Nc;
  int colh = lane & 15, rbase = (lane >> 4) << 2;

  // staging invariants: thread t stages A slot jt0 at ln0, B slots jt0 & jt0+4
  int jt0 = t >> 6, ln0 = t & 63;
  int jA = jh*64 + (jt0 << 4) + (t & 15);
  int gkoff = ((t >> 4) & 3) << 3;
  const unsigned short* conA_base = con + (size_t)(bN + jA)*Hc + gkoff;
  const unsigned short* w1A_base = w1mF + ((size_t)jt0*24 << 9) + (ln0 << 3);
  const unsigned short* w1B_base = w1A_base + ((size_t)4*24 << 9);

  for (int k = t; k < 768; k += 256) a_row[k] = b2f(con[(size_t)(bN + i)*Hc + k]);
  {  // P[i]+b1 staged once (re-read every hc)
    float4 p4 = reinterpret_cast<const float4*>(P + (size_t)(bN + i)*HIDc)[t];
    float4 b4 = reinterpret_cast<const float4*>(b1)[t];
    float4 s4 = { p4.x + b4.x, p4.y + b4.y, p4.z + b4.z, p4.w + b4.w };
    *reinterpret_cast<float4*>(&Pi_lds[4*t]) = s4;
  }

  floatx4 zero = {0.f,0.f,0.f,0.f};
  floatx4 acc2 = zero;
  __syncthreads();

  for (int hc = 0; hc < 8; ++hc) {
    floatx4 acc[8];
    #pragma unroll
    for (int n = 0; n < 8; ++n) acc[n] = zero;

    for (int kc = 0; kc < 24; ++kc) {
      int k0 = kc << 5;
      // ---- stage A (product, 1 slot/thread) and B (2 slots/thread) ----
      {
        ushort8 ca = *reinterpret_cast<const ushort8*>(conA_base + k0);
        size_t woff = ((size_t)(hc*8)*24 + kc) << 9;
        ushort8 wa = *reinterpret_cast<const ushort8*>(w1A_base + woff);
        ushort8 wb = *reinterpret_cast<const ushort8*>(w1B_base + woff);
        floatx4 av0 = *reinterpret_cast<const floatx4*>(&a_row[k0 + gkoff]);
        floatx4 av1 = *reinterpret_cast<const floatx4*>(&a_row[k0 + gkoff + 4]);
        uint4v dA;
        dA[0]=pack2(av0[0]*b2f(ca[0]), av0[1]*b2f(ca[1])); dA[1]=pack2(av0[2]*b2f(ca[2]), av0[3]*b2f(ca[3]));
        dA[2]=pack2(av1[0]*b2f(ca[4]), av1[1]*b2f(ca[5])); dA[3]=pack2(av1[2]*b2f(ca[6]), av1[3]*b2f(ca[7]));
        *reinterpret_cast<uint4v*>(&A_lds[jt0][ln0][0]) = dA;
        *reinterpret_cast<ushort8*>(&B_lds[jt0][ln0][0]) = wa;
        *reinterpret_cast<ushort8*>(&B_lds[jt0+4][ln0][0]) = wb;
      }
      __syncthreads();
      {
        short8 af = *reinterpret_cast<const short8*>(&A_lds[w][lane][0]);
        #pragma unroll
        for (int n = 0; n < 8; ++n) {
          short8 bfr = *reinterpret_cast<const short8*>(&B_lds[n][lane][0]);
          acc[n] = __builtin_amdgcn_mfma_f32_16x16x32_bf16(af, bfr, acc[n], 0,0,0);
        }
      }
      __syncthreads();
    }

    // -------- epilogue: W2 stage (custom k-map) + tanh + hidF + GEMM2 --------
    {
      int ksW = t >> 6, lnW = t & 63, colW = lnW & 15, ksegW = (lnW >> 4) & 3;
      const float* w2p = W2 + (size_t)(hc*128 + ksW*4 + ksegW)*Lc + colW;   // e stride = 16 rows
      uint4v dW;
      dW[0] = pack2(w2p[0],     w2p[256]);
      dW[1] = pack2(w2p[2*256], w2p[3*256]);
      dW[2] = pack2(w2p[4*256], w2p[5*256]);
      dW[3] = pack2(w2p[6*256], w2p[7*256]);
      *reinterpret_cast<uint4v*>(&W2_lds[ksW][lnW][0]) = dW;
    }
    float pb[8];
    #pragma unroll
    for (int n = 0; n < 8; ++n) pb[n] = Pi_lds[hc*128 + n*16 + colh];

    int ksH = colh >> 2;
    int laneH_lo = (colh & 3) << 4;
    #pragma unroll
    for (int r = 0; r < 4; ++r) {
      int jl = rbase + r;
      int j = jh*64 + w*16 + jl;
      const float* qp = Q + (size_t)(bN + j)*HIDc + hc*128 + colh;
      float tv[8];
      #pragma unroll
      for (int n = 0; n < 8; ++n)
        tv[n] = tanh_fast(acc[n][r] + pb[n] + qp[n*16]);
      uint4v hv;
      hv[0] = pack2(tv[0], tv[1]); hv[1] = pack2(tv[2], tv[3]);
      hv[2] = pack2(tv[4], tv[5]); hv[3] = pack2(tv[6], tv[7]);
      unsigned addr16 = ((unsigned)((w*4 + ksH)*64 + (jl | laneH_lo))) ^ (unsigned)(colh & 7);
      *reinterpret_cast<uint4v*>(hidb + addr16*16) = hv;
    }
    __syncthreads();
    #pragma unroll
    for (int ks = 0; ks < 4; ++ks) {
      unsigned addr16 = ((unsigned)((w*4 + ks)*64 + lane)) ^ (unsigned)((ks*4 + (lane >> 4)) & 7);
      short8 a2  = *reinterpret_cast<const short8*>(hidb + addr16*16);
      short8 b2v = *reinterpret_cast<const short8*>(&W2_lds[ks][lane][0]);
      acc2 = __builtin_amdgcn_mfma_f32_16x16x32_bf16(a2, b2v, acc2, 0,0,0);
    }
    __syncthreads();
  }

  float bl = b2[colh];
  #pragma unroll
  for (int r = 0; r < 4; ++r) {
    int j = jh*64 + w*16 + rbase + r;
    out[((size_t)bi*Nc + j)*Lc + colh] = acc2[r] + bl;
  }
}

extern "C" void kernel_launch(void* const* d_in, const int* in_sizes, int n_in,
                              void* d_out, int out_size, void* d_ws, size_t ws_size,
                              hipStream_t stream) {
  const float* AH = (const float*)d_in[0];
  const int*   ST = (const int*)d_in[1];
  const float* W1 = (const float*)d_in[2];
  const float* b1 = (const float*)d_in[3];
  const float* W2 = (const float*)d_in[4];
  const float* b2 = (const float*)d_in[5];
  float* out = (float*)d_out;

  char* ws = (char*)d_ws;
  unsigned short* con  = (unsigned short*)ws;                //   786,432 B
  unsigned short* w1mF = (unsigned short*)(ws +   786432);   // 1,572,864 B
  unsigned short* wPQF = (unsigned short*)(ws +  2359296);   // 3,145,728 B
  float* P = (float*)(ws + 5505024);                         // 2,097,152 B
  float* Q = (float*)(ws + 7602176);                         // 2,097,152 B

  k_gather<<<512, 256, 0, stream>>>(AH, ST, con);
  k_w1m<<<384, 256, 0, stream>>>(W1, w1mF);
  k_wpq<<<768, 256, 0, stream>>>(W1, wPQF);
  k_pq<<<256, 256, 0, stream>>>(con, wPQF, P, Q);
  k_main<<<1024, 256, 0, stream>>>(con, w1mF, P, Q, b1, W2, b2, out);
}